// Round 1
// baseline (319.808 us; speedup 1.0000x reference)
//
#include <hip/hip_runtime.h>
#include <stdint.h>
#include <stddef.h>
#include <algorithm>

// Problem constants (fixed by the reference file)
#define BATCH  1024
#define S1     25
#define S2     10
#define DIM    256
#define NNEIB  64
#define L2ROWS (BATCH * S1)          // 25600
#define MROWS  (BATCH + BATCH * S1)  // 26624 rows for layer-1 aggregation

struct Perm25 { int p[S1]; };
struct Perm10 { int p[S2]; };

// ======================= host-side JAX threefry replication ==================
// Threefry-2x32, 20 rounds (JAX reference cipher).
static inline uint32_t rotl_(uint32_t x, int d) { return (x << d) | (x >> (32 - d)); }

static void tf2x32(uint32_t k0, uint32_t k1, uint32_t x0, uint32_t x1,
                   uint32_t* o0, uint32_t* o1) {
  const uint32_t ks0 = k0, ks1 = k1, ks2 = k0 ^ k1 ^ 0x1BD11BDAu;
  static const int R[8] = {13, 15, 26, 6, 17, 29, 16, 24};
  x0 += ks0; x1 += ks1;
  for (int g = 0; g < 5; ++g) {
    const int* rr = R + (g & 1) * 4;
    for (int i = 0; i < 4; i++) { x0 += x1; x1 = rotl_(x1, rr[i]); x1 ^= x0; }
    uint32_t a, b;
    switch (g) {
      default:
      case 0: a = ks1; b = ks2; break;
      case 1: a = ks2; b = ks0; break;
      case 2: a = ks0; b = ks1; break;
      case 3: a = ks1; b = ks2; break;
      case 4: a = ks2; b = ks0; break;
    }
    x0 += a; x1 = x1 + b + (uint32_t)(g + 1);
  }
  *o0 = x0; *o1 = x1;
}

// jax.random.permutation(fold_in(key(42), li), 64) -> first n entries.
// PARTITIONABLE threefry mode (modern JAX default):
//   fold_in: key' = TF(key; 0, li)
//   split(2) fold-like: subkey = keys[1] = TF(key'; 0, 1)
//   random_bits(32, (64,)): bits[i] = o0 ^ o1 of TF(subkey; 0, i)
//   one sort round (size 64): stable argsort ascending of bits over arange(64)
// FALLBACK (legacy mode, flip if absmax ~O(1)):
//   split: counts [0,1,2,3]; lanes (0,2),(1,3); subkey=(lane0.o1, lane1.o1)
//   bits: lanes i<32: (i, i+32); bits[i]=o0_i, bits[i+32]=o1_i (no xor)
static void compute_perm(uint32_t li, int n, int* out) {
  uint32_t k0, k1, s0, s1;
  tf2x32(0u, 42u, 0u, li, &k0, &k1);   // fold_in(key(42), li)
  tf2x32(k0, k1, 0u, 1u, &s0, &s1);    // subkey = split(key')[1] (fold-like)
  uint32_t bits[NNEIB];
  for (int i = 0; i < NNEIB; i++) {
    uint32_t a, b;
    tf2x32(s0, s1, 0u, (uint32_t)i, &a, &b);
    bits[i] = a ^ b;
  }
  int idx[NNEIB];
  for (int i = 0; i < NNEIB; i++) idx[i] = i;
  std::stable_sort(idx, idx + NNEIB, [&](int A, int B) { return bits[A] < bits[B]; });
  for (int j = 0; j < n; j++) out[j] = idx[j];
}

// ================================ kernels ====================================

// Layer-0 sampling: growB[0..1023] = ids; growB[1024 + i*25 + j] = idx1 sample;
// w1 = normalized weights per batch node.
__global__ __launch_bounds__(256) void sample1_k(
    const int* __restrict__ ids, const int* __restrict__ dix,
    const float* __restrict__ dval, int* __restrict__ growB,
    float* __restrict__ w1, Perm25 pm) {
  int i = blockIdx.x * 256 + threadIdx.x;
  if (i >= BATCH) return;
  int nid = ids[i];
  growB[i] = nid;
  const float* vr = dval + (size_t)nid * NNEIB;
  const int* ir = dix + (size_t)nid * NNEIB;
  float v[S1];
  float s = 0.f;
  for (int j = 0; j < S1; j++) { v[j] = vr[pm.p[j]]; s += v[j]; }
  float inv = 1.f / (s + 1e-10f);
  for (int j = 0; j < S1; j++) {
    w1[i * S1 + j] = v[j] * inv;
    growB[BATCH + i * S1 + j] = ir[pm.p[j]];
  }
}

// Layer-1 sampling from the 25600 layer-0 samples.
__global__ __launch_bounds__(256) void sample2_k(
    const int* __restrict__ idx1, const int* __restrict__ dix,
    const float* __restrict__ dval, int* __restrict__ idx2,
    float* __restrict__ w2, Perm10 pm) {
  int p = blockIdx.x * 256 + threadIdx.x;
  if (p >= L2ROWS) return;
  int nid = idx1[p];
  const float* vr = dval + (size_t)nid * NNEIB;
  const int* ir = dix + (size_t)nid * NNEIB;
  float v[S2];
  float s = 0.f;
  for (int j = 0; j < S2; j++) { v[j] = vr[pm.p[j]]; s += v[j]; }
  float inv = 1.f / (s + 1e-10f);
  for (int j = 0; j < S2; j++) {
    w2[p * S2 + j] = v[j] * inv;
    idx2[p * S2 + j] = ir[pm.p[j]];
  }
}

// Weighted neighbor mean into M1 [MROWS x 256].
// rows 0..1023: 25 neighbors (idx1/w1); rows 1024..: 10 neighbors (idx2/w2).
__global__ __launch_bounds__(256) void wm_neigh_k(
    const float* __restrict__ feats, const int* __restrict__ idx1,
    const float* __restrict__ w1, const int* __restrict__ idx2,
    const float* __restrict__ w2, float* __restrict__ M1) {
  __shared__ int snbr[S1];
  __shared__ float sw[S1];
  int r = blockIdx.x, t = threadIdx.x;
  int s, base;
  const int* nb;
  const float* ww;
  if (r < BATCH) { s = S1; base = r * S1; nb = idx1; ww = w1; }
  else           { s = S2; base = (r - BATCH) * S2; nb = idx2; ww = w2; }
  if (t < s) { snbr[t] = nb[base + t]; sw[t] = ww[base + t]; }
  __syncthreads();
  float acc = 0.f;
  for (int j = 0; j < s; j++) acc += sw[j] * feats[(size_t)snbr[j] * DIM + t];
  M1[(size_t)r * DIM + t] = acc;
}

// Weighted mean of H-rows (layer-2 neighbor aggregation) into M2 [1024 x 256].
__global__ __launch_bounds__(256) void wm2_k(
    const float* __restrict__ H, const float* __restrict__ w1,
    float* __restrict__ M2) {
  __shared__ float sw[S1];
  int i = blockIdx.x, t = threadIdx.x;
  if (t < S1) sw[t] = w1[i * S1 + t];
  __syncthreads();
  const float* hb = H + (size_t)(BATCH + i * S1) * DIM + t;
  float acc = 0.f;
  for (int j = 0; j < S1; j++) acc += sw[j] * hb[(size_t)j * DIM];
  M2[(size_t)i * DIM + t] = acc;
}

// Fused GEMM: Out[r] = relu( X[r] @ Wx + M[r] @ Wn + bx + bn ),
// i.e. C[M x 256] = A[M x 512] @ [Wx; Wn], A[r, k<256] = Xsrc[xrow(r)][k],
// A[r, k>=256] = Msrc[r][k-256]. fp32 VALU, 64x64 tile, BK=16, 4x4 per thread.
#define GBM 64
#define GBN 64
#define GBK 16
__global__ __launch_bounds__(256) void gemm_agg_k(
    const float* __restrict__ Xsrc, const int* __restrict__ grow,
    const float* __restrict__ Msrc, const float* __restrict__ Wx,
    const float* __restrict__ Wn, const float* __restrict__ bx,
    const float* __restrict__ bn, float* __restrict__ Out, int M) {
  __shared__ float As[GBK][GBM + 4];
  __shared__ float Bs[GBK][GBN + 4];
  int t = threadIdx.x;
  int tx = t & 15, ty = t >> 4;
  int row0 = blockIdx.x * GBM;
  int col0 = blockIdx.y * GBN;

  // A-load mapping: 4 consecutive k per thread
  int arow = t >> 2;            // 0..63
  int akoff = (t & 3) * 4;      // 0,4,8,12
  int gr = row0 + arow;
  bool valid = gr < M;
  int xrow = 0;
  if (valid) xrow = grow ? grow[gr] : gr;
  // B-load mapping
  int bkk = t >> 4;             // 0..15
  int bnoff = (t & 15) * 4;     // 0..60

  float acc[4][4] = {};
  for (int k0 = 0; k0 < 2 * DIM; k0 += GBK) {
    float4 av = make_float4(0.f, 0.f, 0.f, 0.f);
    if (valid) {
      int kg = k0 + akoff;
      const float* src = (kg < DIM) ? (Xsrc + (size_t)xrow * DIM + kg)
                                    : (Msrc + (size_t)gr * DIM + (kg - DIM));
      av = *(const float4*)src;
    }
    As[akoff + 0][arow] = av.x;
    As[akoff + 1][arow] = av.y;
    As[akoff + 2][arow] = av.z;
    As[akoff + 3][arow] = av.w;
    {
      int kg = k0 + bkk;
      const float* wsrc = (kg < DIM) ? (Wx + (size_t)kg * DIM + col0 + bnoff)
                                     : (Wn + (size_t)(kg - DIM) * DIM + col0 + bnoff);
      *(float4*)&Bs[bkk][bnoff] = *(const float4*)wsrc;
    }
    __syncthreads();
#pragma unroll
    for (int k = 0; k < GBK; k++) {
      float4 a = *(const float4*)&As[k][ty * 4];
      float4 b = *(const float4*)&Bs[k][tx * 4];
      acc[0][0] += a.x * b.x; acc[0][1] += a.x * b.y; acc[0][2] += a.x * b.z; acc[0][3] += a.x * b.w;
      acc[1][0] += a.y * b.x; acc[1][1] += a.y * b.y; acc[1][2] += a.y * b.z; acc[1][3] += a.y * b.w;
      acc[2][0] += a.z * b.x; acc[2][1] += a.z * b.y; acc[2][2] += a.z * b.z; acc[2][3] += a.z * b.w;
      acc[3][0] += a.w * b.x; acc[3][1] += a.w * b.y; acc[3][2] += a.w * b.z; acc[3][3] += a.w * b.w;
    }
    __syncthreads();
  }
  // epilogue: bias + relu, vectorized store
  int c = col0 + tx * 4;
  float4 bxv = *(const float4*)&bx[c];
  float4 bnv = *(const float4*)&bn[c];
  float bias[4] = {bxv.x + bnv.x, bxv.y + bnv.y, bxv.z + bnv.z, bxv.w + bnv.w};
#pragma unroll
  for (int i = 0; i < 4; i++) {
    int r = row0 + ty * 4 + i;
    if (r >= M) continue;
    float4 o;
    o.x = fmaxf(acc[i][0] + bias[0], 0.f);
    o.y = fmaxf(acc[i][1] + bias[1], 0.f);
    o.z = fmaxf(acc[i][2] + bias[2], 0.f);
    o.w = fmaxf(acc[i][3] + bias[3], 0.f);
    *(float4*)&Out[(size_t)r * DIM + c] = o;
  }
}

// ================================ launcher ===================================
static inline size_t align256(size_t x) { return (x + 255) & ~(size_t)255; }

extern "C" void kernel_launch(void* const* d_in, const int* in_sizes, int n_in,
                              void* d_out, int out_size, void* d_ws, size_t ws_size,
                              hipStream_t stream) {
  const int*   ids  = (const int*)d_in[0];
  const int*   dix  = (const int*)d_in[1];
  const float* dval = (const float*)d_in[2];
  const float* feats= (const float*)d_in[3];
  const float* Wx1  = (const float*)d_in[4];
  const float* bx1  = (const float*)d_in[5];
  const float* Wn1  = (const float*)d_in[6];
  const float* bn1  = (const float*)d_in[7];
  const float* Wx2  = (const float*)d_in[8];
  const float* bx2  = (const float*)d_in[9];
  const float* Wn2  = (const float*)d_in[10];
  const float* bn2  = (const float*)d_in[11];
  float* out = (float*)d_out;

  // Host-side PRNG replication (fixed constants; identical every call).
  Perm25 p25;
  Perm10 p10;
  compute_perm(0u, S1, p25.p);
  compute_perm(1u, S2, p10.p);

  // Workspace carve-up (~58 MB total).
  char* w = (char*)d_ws;
  int*   growB = (int*)w;   w += align256(sizeof(int) * MROWS);          // [ids | idx1]
  float* w1    = (float*)w; w += align256(sizeof(float) * L2ROWS);
  int*   idx2  = (int*)w;   w += align256(sizeof(int) * L2ROWS * S2);
  float* w2    = (float*)w; w += align256(sizeof(float) * L2ROWS * S2);
  float* M1    = (float*)w; w += align256(sizeof(float) * (size_t)MROWS * DIM);
  float* H     = (float*)w; w += align256(sizeof(float) * (size_t)MROWS * DIM);
  float* M2    = (float*)w; w += align256(sizeof(float) * (size_t)BATCH * DIM);
  int* idx1 = growB + BATCH;

  sample1_k<<<(BATCH + 255) / 256, 256, 0, stream>>>(ids, dix, dval, growB, w1, p25);
  sample2_k<<<(L2ROWS + 255) / 256, 256, 0, stream>>>(idx1, dix, dval, idx2, w2, p10);
  wm_neigh_k<<<MROWS, 256, 0, stream>>>(feats, idx1, w1, idx2, w2, M1);
  gemm_agg_k<<<dim3(MROWS / GBM, DIM / GBN), 256, 0, stream>>>(
      feats, growB, M1, Wx1, Wn1, bx1, bn1, H, MROWS);
  wm2_k<<<BATCH, 256, 0, stream>>>(H, w1, M2);
  gemm_agg_k<<<dim3(BATCH / GBM, DIM / GBN), 256, 0, stream>>>(
      H, nullptr, M2, Wx2, Wn2, bx2, bn2, out, BATCH);
}

// Round 2
// 210.645 us; speedup vs baseline: 1.5182x; 1.5182x over previous
//
#include <hip/hip_runtime.h>
#include <stdint.h>
#include <stddef.h>
#include <algorithm>

// Problem constants (fixed by the reference file)
#define BATCH  1024
#define S1     25
#define S2     10
#define DIM    256
#define NNEIB  64
#define L2ROWS (BATCH * S1)          // 25600
#define MROWS  (BATCH + BATCH * S1)  // 26624 rows for layer-1 aggregation
#define KTOT   512                   // GEMM K = [X | M] = 2*DIM

struct Perm25 { int p[S1]; };
struct Perm10 { int p[S2]; };

typedef __attribute__((ext_vector_type(8))) short short8;
typedef __attribute__((ext_vector_type(4))) float f32x4;

// ======================= host-side JAX threefry replication ==================
static inline uint32_t rotl_(uint32_t x, int d) { return (x << d) | (x >> (32 - d)); }

static void tf2x32(uint32_t k0, uint32_t k1, uint32_t x0, uint32_t x1,
                   uint32_t* o0, uint32_t* o1) {
  const uint32_t ks0 = k0, ks1 = k1, ks2 = k0 ^ k1 ^ 0x1BD11BDAu;
  static const int R[8] = {13, 15, 26, 6, 17, 29, 16, 24};
  x0 += ks0; x1 += ks1;
  for (int g = 0; g < 5; ++g) {
    const int* rr = R + (g & 1) * 4;
    for (int i = 0; i < 4; i++) { x0 += x1; x1 = rotl_(x1, rr[i]); x1 ^= x0; }
    uint32_t a, b;
    switch (g) {
      default:
      case 0: a = ks1; b = ks2; break;
      case 1: a = ks2; b = ks0; break;
      case 2: a = ks0; b = ks1; break;
      case 3: a = ks1; b = ks2; break;
      case 4: a = ks2; b = ks0; break;
    }
    x0 += a; x1 = x1 + b + (uint32_t)(g + 1);
  }
  *o0 = x0; *o1 = x1;
}

// jax.random.permutation(fold_in(key(42), li), 64), partitionable threefry
// (verified correct in R1: absmax 7.8e-3 with fp32 math).
static void compute_perm(uint32_t li, int n, int* out) {
  uint32_t k0, k1, s0, s1;
  tf2x32(0u, 42u, 0u, li, &k0, &k1);   // fold_in(key(42), li)
  tf2x32(k0, k1, 0u, 1u, &s0, &s1);    // subkey = split(key')[1]
  uint32_t bits[NNEIB];
  for (int i = 0; i < NNEIB; i++) {
    uint32_t a, b;
    tf2x32(s0, s1, 0u, (uint32_t)i, &a, &b);
    bits[i] = a ^ b;
  }
  int idx[NNEIB];
  for (int i = 0; i < NNEIB; i++) idx[i] = i;
  std::stable_sort(idx, idx + NNEIB, [&](int A, int B) { return bits[A] < bits[B]; });
  for (int j = 0; j < n; j++) out[j] = idx[j];
}

// ============================ device helpers =================================
__device__ __forceinline__ unsigned short f2bf(float x) {
  union { float f; uint32_t u; } v; v.f = x;
  uint32_t r = (v.u + 0x7FFFu + ((v.u >> 16) & 1u)) >> 16;   // RNE
  return (unsigned short)r;
}
__device__ __forceinline__ float bf2f(unsigned short u) {
  union { uint32_t u; float f; } v; v.u = ((uint32_t)u) << 16;
  return v.f;
}

// ================================ kernels ====================================

// Layer-0 sampling: growB[0..1023] = ids; growB[1024 + i*25 + j] = idx1 sample.
__global__ __launch_bounds__(256) void sample1_k(
    const int* __restrict__ ids, const int* __restrict__ dix,
    const float* __restrict__ dval, int* __restrict__ growB,
    float* __restrict__ w1, Perm25 pm) {
  int i = blockIdx.x * 256 + threadIdx.x;
  if (i >= BATCH) return;
  int nid = ids[i];
  growB[i] = nid;
  const float* vr = dval + (size_t)nid * NNEIB;
  const int* ir = dix + (size_t)nid * NNEIB;
  float v[S1];
  float s = 0.f;
  for (int j = 0; j < S1; j++) { v[j] = vr[pm.p[j]]; s += v[j]; }
  float inv = 1.f / (s + 1e-10f);
  for (int j = 0; j < S1; j++) {
    w1[i * S1 + j] = v[j] * inv;
    growB[BATCH + i * S1 + j] = ir[pm.p[j]];
  }
}

__global__ __launch_bounds__(256) void sample2_k(
    const int* __restrict__ idx1, const int* __restrict__ dix,
    const float* __restrict__ dval, int* __restrict__ idx2,
    float* __restrict__ w2, Perm10 pm) {
  int p = blockIdx.x * 256 + threadIdx.x;
  if (p >= L2ROWS) return;
  int nid = idx1[p];
  const float* vr = dval + (size_t)nid * NNEIB;
  const int* ir = dix + (size_t)nid * NNEIB;
  float v[S2];
  float s = 0.f;
  for (int j = 0; j < S2; j++) { v[j] = vr[pm.p[j]]; s += v[j]; }
  float inv = 1.f / (s + 1e-10f);
  for (int j = 0; j < S2; j++) {
    w2[p * S2 + j] = v[j] * inv;
    idx2[p * S2 + j] = ir[pm.p[j]];
  }
}

// Build bf16 A1 [MROWS x 512]: cols 0..255 = feats[xrow], cols 256..511 =
// weighted neighbor mean. One block per row; t = column.
__global__ __launch_bounds__(256) void stage1_k(
    const float* __restrict__ feats, const int* __restrict__ growB,
    const int* __restrict__ idx1, const float* __restrict__ w1,
    const int* __restrict__ idx2, const float* __restrict__ w2,
    unsigned short* __restrict__ A1) {
  __shared__ int snbr[S1];
  __shared__ float sw[S1];
  int r = blockIdx.x, t = threadIdx.x;
  int s, base;
  const int* nb;
  const float* ww;
  if (r < BATCH) { s = S1; base = r * S1; nb = idx1; ww = w1; }
  else           { s = S2; base = (r - BATCH) * S2; nb = idx2; ww = w2; }
  if (t < s) { snbr[t] = nb[base + t]; sw[t] = ww[base + t]; }
  int xrow = growB[r];
  __syncthreads();
  float xv = feats[(size_t)xrow * DIM + t];
  float acc = 0.f;
  for (int j = 0; j < s; j++) acc += sw[j] * feats[(size_t)snbr[j] * DIM + t];
  A1[(size_t)r * KTOT + t]       = f2bf(xv);
  A1[(size_t)r * KTOT + DIM + t] = f2bf(acc);
}

// Build bf16 A2 [1024 x 512] from bf16 H: X part = H rows 0..1023,
// M part = weighted mean of H rows 1024 + i*25 + j with w1.
__global__ __launch_bounds__(256) void stage2_k(
    const unsigned short* __restrict__ H, const float* __restrict__ w1,
    unsigned short* __restrict__ A2) {
  __shared__ float sw[S1];
  int i = blockIdx.x, t = threadIdx.x;
  if (t < S1) sw[t] = w1[i * S1 + t];
  __syncthreads();
  const unsigned short* hb = H + (size_t)(BATCH + i * S1) * DIM + t;
  float acc = 0.f;
  for (int j = 0; j < S1; j++) acc += sw[j] * bf2f(hb[(size_t)j * DIM]);
  A2[(size_t)i * KTOT + t]       = H[(size_t)i * DIM + t];
  A2[(size_t)i * KTOT + DIM + t] = f2bf(acc);
}

// Convert + transpose weights: Wt[n][k] (bf16, n=0..255, k=0..511) from
// fp32 Wx[k][n] (k<256) and Wn[k-256][n].
__global__ __launch_bounds__(256) void convw_k(
    const float* __restrict__ Wx, const float* __restrict__ Wn,
    unsigned short* __restrict__ Wt) {
  int idx = blockIdx.x * 256 + threadIdx.x;   // 0 .. 256*512-1
  int n = idx >> 9;
  int k = idx & 511;
  float v = (k < DIM) ? Wx[(size_t)k * DIM + n] : Wn[(size_t)(k - DIM) * DIM + n];
  Wt[(size_t)n * KTOT + k] = f2bf(v);
}

// bf16 MFMA GEMM: Out[M x 256] = relu(A[M x 512] @ Wt^T + bx + bn).
// BM=128, BN=64, BK=32; 4 waves, wave w owns rows [w*32, w*32+32) x all 64 cols.
// Fragment layouts (HW-verified, m89/m91): A[m=lane&15][k=quad*8+j],
// B=Wt[n=lane&15][k=quad*8+j], D col=lane&15 row=quad*4+reg.
// M must be a multiple of 128 (26624 = 208*128, 1024 = 8*128).
#define BM 128
#define BN 64
#define BK 32
#define LPAD 40   // LDS row stride in bf16: 80 B = 16B-aligned, 20-bank stride
template <bool OUT_BF16>
__global__ __launch_bounds__(256) void mfma_gemm_k(
    const unsigned short* __restrict__ A, const unsigned short* __restrict__ Wt,
    const float* __restrict__ bx, const float* __restrict__ bn,
    void* __restrict__ OutP, int M) {
  __shared__ __align__(16) unsigned short As[BM][LPAD];
  __shared__ __align__(16) unsigned short Bs[BN][LPAD];
  int t = threadIdx.x;
  int wave = t >> 6;
  int lane = t & 63;
  int quad = lane >> 4;
  int l16 = lane & 15;
  int row0 = blockIdx.x * BM;
  int col0 = blockIdx.y * BN;

  f32x4 acc[2][4];
#pragma unroll
  for (int i = 0; i < 2; i++)
#pragma unroll
    for (int j = 0; j < 4; j++) acc[i][j] = (f32x4){0.f, 0.f, 0.f, 0.f};

  int lr = t >> 2;            // 0..63
  int lq = (t & 3) * 8;       // k element offset: 0,8,16,24 (16B chunks)

  for (int k0 = 0; k0 < KTOT; k0 += BK) {
    // A tile: 128 rows x 32 k. Each thread: 16B from row lr and row lr+64.
    *(f32x4*)&As[lr][lq]      = *(const f32x4*)&A[(size_t)(row0 + lr) * KTOT + k0 + lq];
    *(f32x4*)&As[lr + 64][lq] = *(const f32x4*)&A[(size_t)(row0 + lr + 64) * KTOT + k0 + lq];
    // B tile: 64 cols x 32 k. Each thread: one 16B chunk.
    *(f32x4*)&Bs[lr][lq]      = *(const f32x4*)&Wt[(size_t)(col0 + lr) * KTOT + k0 + lq];
    __syncthreads();

    short8 a0 = *(const short8*)&As[wave * 32 + l16][quad * 8];
    short8 a1 = *(const short8*)&As[wave * 32 + 16 + l16][quad * 8];
    short8 b0 = *(const short8*)&Bs[l16][quad * 8];
    short8 b1 = *(const short8*)&Bs[16 + l16][quad * 8];
    short8 b2 = *(const short8*)&Bs[32 + l16][quad * 8];
    short8 b3 = *(const short8*)&Bs[48 + l16][quad * 8];

    acc[0][0] = __builtin_amdgcn_mfma_f32_16x16x32_bf16(a0, b0, acc[0][0], 0, 0, 0);
    acc[0][1] = __builtin_amdgcn_mfma_f32_16x16x32_bf16(a0, b1, acc[0][1], 0, 0, 0);
    acc[0][2] = __builtin_amdgcn_mfma_f32_16x16x32_bf16(a0, b2, acc[0][2], 0, 0, 0);
    acc[0][3] = __builtin_amdgcn_mfma_f32_16x16x32_bf16(a0, b3, acc[0][3], 0, 0, 0);
    acc[1][0] = __builtin_amdgcn_mfma_f32_16x16x32_bf16(a1, b0, acc[1][0], 0, 0, 0);
    acc[1][1] = __builtin_amdgcn_mfma_f32_16x16x32_bf16(a1, b1, acc[1][1], 0, 0, 0);
    acc[1][2] = __builtin_amdgcn_mfma_f32_16x16x32_bf16(a1, b2, acc[1][2], 0, 0, 0);
    acc[1][3] = __builtin_amdgcn_mfma_f32_16x16x32_bf16(a1, b3, acc[1][3], 0, 0, 0);
    __syncthreads();
  }

  // Epilogue: bias + relu. D layout: col = l16 (+16j), row = quad*4 + reg.
#pragma unroll
  for (int j = 0; j < 4; j++) {
    int c = col0 + j * 16 + l16;
    float bias = bx[c] + bn[c];
#pragma unroll
    for (int i = 0; i < 2; i++) {
#pragma unroll
      for (int reg = 0; reg < 4; reg++) {
        int r = row0 + wave * 32 + i * 16 + quad * 4 + reg;
        float v = fmaxf(acc[i][j][reg] + bias, 0.f);
        if (OUT_BF16)
          ((unsigned short*)OutP)[(size_t)r * DIM + c] = f2bf(v);
        else
          ((float*)OutP)[(size_t)r * DIM + c] = v;
      }
    }
  }
}

// ================================ launcher ===================================
static inline size_t align256(size_t x) { return (x + 255) & ~(size_t)255; }

extern "C" void kernel_launch(void* const* d_in, const int* in_sizes, int n_in,
                              void* d_out, int out_size, void* d_ws, size_t ws_size,
                              hipStream_t stream) {
  const int*   ids  = (const int*)d_in[0];
  const int*   dix  = (const int*)d_in[1];
  const float* dval = (const float*)d_in[2];
  const float* feats= (const float*)d_in[3];
  const float* Wx1  = (const float*)d_in[4];
  const float* bx1  = (const float*)d_in[5];
  const float* Wn1  = (const float*)d_in[6];
  const float* bn1  = (const float*)d_in[7];
  const float* Wx2  = (const float*)d_in[8];
  const float* bx2  = (const float*)d_in[9];
  const float* Wn2  = (const float*)d_in[10];
  const float* bn2  = (const float*)d_in[11];
  float* out = (float*)d_out;

  Perm25 p25;
  Perm10 p10;
  compute_perm(0u, S1, p25.p);
  compute_perm(1u, S2, p10.p);

  // Workspace carve-up (~45 MB).
  char* w = (char*)d_ws;
  int*            growB = (int*)w;            w += align256(sizeof(int) * MROWS);
  float*          w1    = (float*)w;          w += align256(sizeof(float) * L2ROWS);
  int*            idx2  = (int*)w;            w += align256(sizeof(int) * (size_t)L2ROWS * S2);
  float*          w2    = (float*)w;          w += align256(sizeof(float) * (size_t)L2ROWS * S2);
  unsigned short* A1    = (unsigned short*)w; w += align256(2 * (size_t)MROWS * KTOT);
  unsigned short* Hb    = (unsigned short*)w; w += align256(2 * (size_t)MROWS * DIM);
  unsigned short* A2    = (unsigned short*)w; w += align256(2 * (size_t)BATCH * KTOT);
  unsigned short* Wt1   = (unsigned short*)w; w += align256(2 * (size_t)DIM * KTOT);
  unsigned short* Wt2   = (unsigned short*)w; w += align256(2 * (size_t)DIM * KTOT);
  int* idx1 = growB + BATCH;

  convw_k<<<(DIM * KTOT) / 256, 256, 0, stream>>>(Wx1, Wn1, Wt1);
  convw_k<<<(DIM * KTOT) / 256, 256, 0, stream>>>(Wx2, Wn2, Wt2);
  sample1_k<<<(BATCH + 255) / 256, 256, 0, stream>>>(ids, dix, dval, growB, w1, p25);
  sample2_k<<<(L2ROWS + 255) / 256, 256, 0, stream>>>(idx1, dix, dval, idx2, w2, p10);
  stage1_k<<<MROWS, 256, 0, stream>>>(feats, growB, idx1, w1, idx2, w2, A1);
  mfma_gemm_k<true><<<dim3(MROWS / BM, DIM / BN), 256, 0, stream>>>(
      A1, Wt1, bx1, bn1, Hb, MROWS);
  stage2_k<<<BATCH, 256, 0, stream>>>(Hb, w1, A2);
  mfma_gemm_k<false><<<dim3(BATCH / BM, DIM / BN), 256, 0, stream>>>(
      A2, Wt2, bx2, bn2, out, BATCH);
}

// Round 3
// 202.248 us; speedup vs baseline: 1.5813x; 1.0415x over previous
//
#include <hip/hip_runtime.h>
#include <stdint.h>
#include <stddef.h>
#include <algorithm>

// Problem constants (fixed by the reference file)
#define BATCH  1024
#define S1     25
#define S2     10
#define DIM    256
#define NNEIB  64
#define L2ROWS (BATCH * S1)          // 25600
#define MROWS  (BATCH + BATCH * S1)  // 26624 (multiple of 128)
#define KTOT   512                   // GEMM K = [X | M]
#define NFEAT  50000

struct Perm25 { int p[S1]; };
struct Perm10 { int p[S2]; };

typedef __attribute__((ext_vector_type(8))) short short8;
typedef __attribute__((ext_vector_type(4))) float f32x4;

// ======================= host-side JAX threefry replication ==================
static inline uint32_t rotl_(uint32_t x, int d) { return (x << d) | (x >> (32 - d)); }

static void tf2x32(uint32_t k0, uint32_t k1, uint32_t x0, uint32_t x1,
                   uint32_t* o0, uint32_t* o1) {
  const uint32_t ks0 = k0, ks1 = k1, ks2 = k0 ^ k1 ^ 0x1BD11BDAu;
  static const int R[8] = {13, 15, 26, 6, 17, 29, 16, 24};
  x0 += ks0; x1 += ks1;
  for (int g = 0; g < 5; ++g) {
    const int* rr = R + (g & 1) * 4;
    for (int i = 0; i < 4; i++) { x0 += x1; x1 = rotl_(x1, rr[i]); x1 ^= x0; }
    uint32_t a, b;
    switch (g) {
      default:
      case 0: a = ks1; b = ks2; break;
      case 1: a = ks2; b = ks0; break;
      case 2: a = ks0; b = ks1; break;
      case 3: a = ks1; b = ks2; break;
      case 4: a = ks2; b = ks0; break;
    }
    x0 += a; x1 = x1 + b + (uint32_t)(g + 1);
  }
  *o0 = x0; *o1 = x1;
}

// jax.random.permutation(fold_in(key(42), li), 64), partitionable threefry
// (verified correct R1/R2).
static void compute_perm(uint32_t li, int n, int* out) {
  uint32_t k0, k1, s0, s1;
  tf2x32(0u, 42u, 0u, li, &k0, &k1);
  tf2x32(k0, k1, 0u, 1u, &s0, &s1);
  uint32_t bits[NNEIB];
  for (int i = 0; i < NNEIB; i++) {
    uint32_t a, b;
    tf2x32(s0, s1, 0u, (uint32_t)i, &a, &b);
    bits[i] = a ^ b;
  }
  int idx[NNEIB];
  for (int i = 0; i < NNEIB; i++) idx[i] = i;
  std::stable_sort(idx, idx + NNEIB, [&](int A, int B) { return bits[A] < bits[B]; });
  for (int j = 0; j < n; j++) out[j] = idx[j];
}

// ============================ device helpers =================================
__device__ __forceinline__ unsigned short f2bf(float x) {
  union { float f; uint32_t u; } v; v.f = x;
  uint32_t r = (v.u + 0x7FFFu + ((v.u >> 16) & 1u)) >> 16;   // RNE
  return (unsigned short)r;
}
__device__ __forceinline__ float bfbits2f(uint32_t lo16) {
  union { uint32_t u; float f; } v; v.u = lo16 << 16;
  return v.f;
}

// ================================ kernels ====================================

// feats fp32 -> bf16 (packed). 4 elements/thread.
__global__ __launch_bounds__(256) void convf_k(
    const float* __restrict__ feats, uint32_t* __restrict__ fb) {
  int i = blockIdx.x * 256 + threadIdx.x;          // 0 .. NFEAT*DIM/4-1
  f32x4 v = *(const f32x4*)&feats[(size_t)i * 4];
  uint32_t lo = f2bf(v.x) | ((uint32_t)f2bf(v.y) << 16);
  uint32_t hi = f2bf(v.z) | ((uint32_t)f2bf(v.w) << 16);
  fb[(size_t)i * 2]     = lo;
  fb[(size_t)i * 2 + 1] = hi;
}

// Layer-0 sampling: growB[0..1023] = ids; growB[1024 + i*25 + j] = sample.
__global__ __launch_bounds__(256) void sample1_k(
    const int* __restrict__ ids, const int* __restrict__ dix,
    const float* __restrict__ dval, int* __restrict__ growB,
    float* __restrict__ w1, Perm25 pm) {
  int i = blockIdx.x * 256 + threadIdx.x;
  if (i >= BATCH) return;
  int nid = ids[i];
  growB[i] = nid;
  const float* vr = dval + (size_t)nid * NNEIB;
  const int* ir = dix + (size_t)nid * NNEIB;
  float v[S1];
  float s = 0.f;
  for (int j = 0; j < S1; j++) { v[j] = vr[pm.p[j]]; s += v[j]; }
  float inv = 1.f / (s + 1e-10f);
  for (int j = 0; j < S1; j++) {
    w1[i * S1 + j] = v[j] * inv;
    growB[BATCH + i * S1 + j] = ir[pm.p[j]];
  }
}

__global__ __launch_bounds__(256) void sample2_k(
    const int* __restrict__ idx1, const int* __restrict__ dix,
    const float* __restrict__ dval, int* __restrict__ idx2,
    float* __restrict__ w2, Perm10 pm) {
  int p = blockIdx.x * 256 + threadIdx.x;
  if (p >= L2ROWS) return;
  int nid = idx1[p];
  const float* vr = dval + (size_t)nid * NNEIB;
  const int* ir = dix + (size_t)nid * NNEIB;
  float v[S2];
  float s = 0.f;
  for (int j = 0; j < S2; j++) { v[j] = vr[pm.p[j]]; s += v[j]; }
  float inv = 1.f / (s + 1e-10f);
  for (int j = 0; j < S2; j++) {
    w2[p * S2 + j] = v[j] * inv;
    idx2[p * S2 + j] = ir[pm.p[j]];
  }
}

// Build bf16 A1 [MROWS x 512] from bf16 feats. Wave-per-row: 4 rows/block.
// Lane covers 4 columns (uint2 = 4 bf16). Neighbor idx/weight via shuffles.
__global__ __launch_bounds__(256) void stage1_k(
    const uint2* __restrict__ fb, const int* __restrict__ growB,
    const int* __restrict__ idx1, const float* __restrict__ w1,
    const int* __restrict__ idx2, const float* __restrict__ w2,
    uint2* __restrict__ A1) {
  int wave = threadIdx.x >> 6, lane = threadIdx.x & 63;
  int r = blockIdx.x * 4 + wave;
  int s;
  const int* nb;
  const float* ww;
  if (r < BATCH) { s = S1; nb = idx1 + (size_t)r * S1; ww = w1 + (size_t)r * S1; }
  else { s = S2; int b = r - BATCH; nb = idx2 + (size_t)b * S2; ww = w2 + (size_t)b * S2; }
  int nbl = 0;
  float wl = 0.f;
  if (lane < s) { nbl = nb[lane]; wl = ww[lane]; }
  int xrow = growB[r];
  // X part: straight bf16 copy (identical rounding to R2's fp32->bf16 path).
  A1[(size_t)r * 128 + lane] = fb[(size_t)xrow * 64 + lane];
  // M part: weighted mean of bf16 neighbor rows, fp32 accumulate.
  float a0 = 0.f, a1 = 0.f, a2 = 0.f, a3 = 0.f;
  for (int j = 0; j < s; j++) {
    int nid = __shfl(nbl, j);
    float wj = __shfl(wl, j);
    uint2 u = fb[(size_t)nid * 64 + lane];
    a0 += wj * bfbits2f(u.x & 0xffffu);
    a1 += wj * bfbits2f(u.x >> 16);
    a2 += wj * bfbits2f(u.y & 0xffffu);
    a3 += wj * bfbits2f(u.y >> 16);
  }
  uint2 o;
  o.x = f2bf(a0) | ((uint32_t)f2bf(a1) << 16);
  o.y = f2bf(a2) | ((uint32_t)f2bf(a3) << 16);
  A1[(size_t)r * 128 + 64 + lane] = o;
}

// Build bf16 A2 [1024 x 512] from bf16 H. Wave-per-row, uint2 loads.
__global__ __launch_bounds__(256) void stage2_k(
    const uint2* __restrict__ Hb, const float* __restrict__ w1,
    uint2* __restrict__ A2) {
  int wave = threadIdx.x >> 6, lane = threadIdx.x & 63;
  int i = blockIdx.x * 4 + wave;
  float wl = (lane < S1) ? w1[(size_t)i * S1 + lane] : 0.f;
  A2[(size_t)i * 128 + lane] = Hb[(size_t)i * 64 + lane];   // X copy
  const uint2* hb = Hb + (size_t)(BATCH + i * S1) * 64 + lane;
  float a0 = 0.f, a1 = 0.f, a2 = 0.f, a3 = 0.f;
  for (int j = 0; j < S1; j++) {
    float wj = __shfl(wl, j);
    uint2 u = hb[(size_t)j * 64];
    a0 += wj * bfbits2f(u.x & 0xffffu);
    a1 += wj * bfbits2f(u.x >> 16);
    a2 += wj * bfbits2f(u.y & 0xffffu);
    a3 += wj * bfbits2f(u.y >> 16);
  }
  uint2 o;
  o.x = f2bf(a0) | ((uint32_t)f2bf(a1) << 16);
  o.y = f2bf(a2) | ((uint32_t)f2bf(a3) << 16);
  A2[(size_t)i * 128 + 64 + lane] = o;
}

// Convert + transpose weights: Wt[n][k] (bf16) from fp32 Wx[k][n], Wn[k-256][n].
__global__ __launch_bounds__(256) void convw_k(
    const float* __restrict__ Wx, const float* __restrict__ Wn,
    unsigned short* __restrict__ Wt) {
  int idx = blockIdx.x * 256 + threadIdx.x;
  int n = idx >> 9;
  int k = idx & 511;
  float v = (k < DIM) ? Wx[(size_t)k * DIM + n] : Wn[(size_t)(k - DIM) * DIM + n];
  Wt[(size_t)n * KTOT + k] = f2bf(v);
}

// bf16 MFMA GEMM: Out[M x 256] = relu(A[M x 512] @ Wt^T + bx + bn).
// Templated tile; 256 threads = 4 waves in a 2x2 wave grid; wave tile
// (TBM/2 x TBN/2); 16x16x32 MFMA. Fragment layouts HW-verified (m89/m91).
#define BK 32
#define LPAD 40   // LDS row stride (bf16): 80 B -> 2-way bank aliasing (free)
template <int TBM, int TBN, bool OUT_BF16>
__global__ __launch_bounds__(256) void gemm_k(
    const unsigned short* __restrict__ A, const unsigned short* __restrict__ Wt,
    const float* __restrict__ bx, const float* __restrict__ bn,
    void* __restrict__ OutP) {
  constexpr int MI = TBM / 32;   // a-frags per wave
  constexpr int NJ = TBN / 32;   // b-frags per wave
  __shared__ __align__(16) unsigned short As[TBM][LPAD];
  __shared__ __align__(16) unsigned short Bs[TBN][LPAD];
  int t = threadIdx.x;
  int wave = t >> 6, lane = t & 63, quad = lane >> 4, l16 = lane & 15;
  int wm = (wave >> 1) * (TBM / 2);
  int wn = (wave & 1) * (TBN / 2);
  int row0 = blockIdx.x * TBM, col0 = blockIdx.y * TBN;

  f32x4 acc[MI][NJ];
#pragma unroll
  for (int i = 0; i < MI; i++)
#pragma unroll
    for (int j = 0; j < NJ; j++) acc[i][j] = (f32x4){0.f, 0.f, 0.f, 0.f};

  int lr = t >> 2;
  int lq = (t & 3) * 8;

  for (int k0 = 0; k0 < KTOT; k0 += BK) {
#pragma unroll
    for (int p = 0; p < TBM / 64; p++)
      *(f32x4*)&As[p * 64 + lr][lq] =
          *(const f32x4*)&A[(size_t)(row0 + p * 64 + lr) * KTOT + k0 + lq];
#pragma unroll
    for (int p = 0; p < TBN / 64; p++)
      *(f32x4*)&Bs[p * 64 + lr][lq] =
          *(const f32x4*)&Wt[(size_t)(col0 + p * 64 + lr) * KTOT + k0 + lq];
    __syncthreads();

    short8 af[MI], bfr[NJ];
#pragma unroll
    for (int i = 0; i < MI; i++)
      af[i] = *(const short8*)&As[wm + i * 16 + l16][quad * 8];
#pragma unroll
    for (int j = 0; j < NJ; j++)
      bfr[j] = *(const short8*)&Bs[wn + j * 16 + l16][quad * 8];
#pragma unroll
    for (int i = 0; i < MI; i++)
#pragma unroll
      for (int j = 0; j < NJ; j++)
        acc[i][j] = __builtin_amdgcn_mfma_f32_16x16x32_bf16(af[i], bfr[j], acc[i][j], 0, 0, 0);
    __syncthreads();
  }

  // Epilogue: bias + relu. D layout: col = l16, row = quad*4 + reg.
  float bias[NJ];
#pragma unroll
  for (int j = 0; j < NJ; j++) {
    int c = col0 + wn + j * 16 + l16;
    bias[j] = bx[c] + bn[c];
  }
#pragma unroll
  for (int i = 0; i < MI; i++) {
#pragma unroll
    for (int j = 0; j < NJ; j++) {
      int c = col0 + wn + j * 16 + l16;
#pragma unroll
      for (int reg = 0; reg < 4; reg++) {
        int r = row0 + wm + i * 16 + quad * 4 + reg;
        float v = fmaxf(acc[i][j][reg] + bias[j], 0.f);
        if (OUT_BF16)
          ((unsigned short*)OutP)[(size_t)r * DIM + c] = f2bf(v);
        else
          ((float*)OutP)[(size_t)r * DIM + c] = v;
      }
    }
  }
}

// ================================ launcher ===================================
static inline size_t align256(size_t x) { return (x + 255) & ~(size_t)255; }

extern "C" void kernel_launch(void* const* d_in, const int* in_sizes, int n_in,
                              void* d_out, int out_size, void* d_ws, size_t ws_size,
                              hipStream_t stream) {
  const int*   ids  = (const int*)d_in[0];
  const int*   dix  = (const int*)d_in[1];
  const float* dval = (const float*)d_in[2];
  const float* feats= (const float*)d_in[3];
  const float* Wx1  = (const float*)d_in[4];
  const float* bx1  = (const float*)d_in[5];
  const float* Wn1  = (const float*)d_in[6];
  const float* bn1  = (const float*)d_in[7];
  const float* Wx2  = (const float*)d_in[8];
  const float* bx2  = (const float*)d_in[9];
  const float* Wn2  = (const float*)d_in[10];
  const float* bn2  = (const float*)d_in[11];
  float* out = (float*)d_out;

  Perm25 p25;
  Perm10 p10;
  compute_perm(0u, S1, p25.p);
  compute_perm(1u, S2, p10.p);

  // Workspace carve-up (~70 MB).
  char* w = (char*)d_ws;
  int*            growB = (int*)w;            w += align256(sizeof(int) * MROWS);
  float*          w1    = (float*)w;          w += align256(sizeof(float) * L2ROWS);
  int*            idx2  = (int*)w;            w += align256(sizeof(int) * (size_t)L2ROWS * S2);
  float*          w2    = (float*)w;          w += align256(sizeof(float) * (size_t)L2ROWS * S2);
  uint32_t*       fb    = (uint32_t*)w;       w += align256(2 * (size_t)NFEAT * DIM);
  unsigned short* A1    = (unsigned short*)w; w += align256(2 * (size_t)MROWS * KTOT);
  unsigned short* Hb    = (unsigned short*)w; w += align256(2 * (size_t)MROWS * DIM);
  unsigned short* A2    = (unsigned short*)w; w += align256(2 * (size_t)BATCH * KTOT);
  unsigned short* Wt1   = (unsigned short*)w; w += align256(2 * (size_t)DIM * KTOT);
  unsigned short* Wt2   = (unsigned short*)w; w += align256(2 * (size_t)DIM * KTOT);
  int* idx1 = growB + BATCH;

  convf_k<<<(NFEAT * DIM / 4) / 256, 256, 0, stream>>>(feats, fb);
  convw_k<<<(DIM * KTOT) / 256, 256, 0, stream>>>(Wx1, Wn1, Wt1);
  convw_k<<<(DIM * KTOT) / 256, 256, 0, stream>>>(Wx2, Wn2, Wt2);
  sample1_k<<<(BATCH + 255) / 256, 256, 0, stream>>>(ids, dix, dval, growB, w1, p25);
  sample2_k<<<(L2ROWS + 255) / 256, 256, 0, stream>>>(idx1, dix, dval, idx2, w2, p10);
  stage1_k<<<MROWS / 4, 256, 0, stream>>>((const uint2*)fb, growB, idx1, w1, idx2, w2,
                                          (uint2*)A1);
  gemm_k<128, 128, true><<<dim3(MROWS / 128, DIM / 128), 256, 0, stream>>>(
      A1, Wt1, bx1, bn1, Hb);
  stage2_k<<<BATCH / 4, 256, 0, stream>>>((const uint2*)Hb, w1, (uint2*)A2);
  gemm_k<64, 64, false><<<dim3(BATCH / 64, DIM / 64), 256, 0, stream>>>(
      A2, Wt2, bx2, bn2, out);
}

// Round 4
// 187.737 us; speedup vs baseline: 1.7035x; 1.0773x over previous
//
#include <hip/hip_runtime.h>
#include <stdint.h>
#include <stddef.h>
#include <algorithm>

// Problem constants (fixed by the reference file)
#define BATCH  1024
#define S1     25
#define S2     10
#define DIM    256
#define NNEIB  64
#define L2ROWS (BATCH * S1)          // 25600
#define MROWS  (BATCH + BATCH * S1)  // 26624 (multiple of 128)
#define KTOT   512                   // GEMM K = [X | M]
#define NFEAT  50000

struct Perm25 { int p[S1]; };
struct Perm10 { int p[S2]; };

typedef __attribute__((ext_vector_type(8))) short short8;
typedef __attribute__((ext_vector_type(4))) float f32x4;

// ======================= host-side JAX threefry replication ==================
static inline uint32_t rotl_(uint32_t x, int d) { return (x << d) | (x >> (32 - d)); }

static void tf2x32(uint32_t k0, uint32_t k1, uint32_t x0, uint32_t x1,
                   uint32_t* o0, uint32_t* o1) {
  const uint32_t ks0 = k0, ks1 = k1, ks2 = k0 ^ k1 ^ 0x1BD11BDAu;
  static const int R[8] = {13, 15, 26, 6, 17, 29, 16, 24};
  x0 += ks0; x1 += ks1;
  for (int g = 0; g < 5; ++g) {
    const int* rr = R + (g & 1) * 4;
    for (int i = 0; i < 4; i++) { x0 += x1; x1 = rotl_(x1, rr[i]); x1 ^= x0; }
    uint32_t a, b;
    switch (g) {
      default:
      case 0: a = ks1; b = ks2; break;
      case 1: a = ks2; b = ks0; break;
      case 2: a = ks0; b = ks1; break;
      case 3: a = ks1; b = ks2; break;
      case 4: a = ks2; b = ks0; break;
    }
    x0 += a; x1 = x1 + b + (uint32_t)(g + 1);
  }
  *o0 = x0; *o1 = x1;
}

// jax.random.permutation(fold_in(key(42), li), 64), partitionable threefry
// (verified correct R1-R3).
static void compute_perm(uint32_t li, int n, int* out) {
  uint32_t k0, k1, s0, s1;
  tf2x32(0u, 42u, 0u, li, &k0, &k1);
  tf2x32(k0, k1, 0u, 1u, &s0, &s1);
  uint32_t bits[NNEIB];
  for (int i = 0; i < NNEIB; i++) {
    uint32_t a, b;
    tf2x32(s0, s1, 0u, (uint32_t)i, &a, &b);
    bits[i] = a ^ b;
  }
  int idx[NNEIB];
  for (int i = 0; i < NNEIB; i++) idx[i] = i;
  std::stable_sort(idx, idx + NNEIB, [&](int A, int B) { return bits[A] < bits[B]; });
  for (int j = 0; j < n; j++) out[j] = idx[j];
}

// ============================ device helpers =================================
__device__ __forceinline__ unsigned short f2bf(float x) {
  union { float f; uint32_t u; } v; v.f = x;
  uint32_t r = (v.u + 0x7FFFu + ((v.u >> 16) & 1u)) >> 16;   // RNE
  return (unsigned short)r;
}
__device__ __forceinline__ float bfbits2f(uint32_t lo16) {
  union { uint32_t u; float f; } v; v.u = lo16 << 16;
  return v.f;
}

// ================================ kernels ====================================

// Fused prep: [0,12500) convf  |  [12500,13012) convw W1 | [13012,13524) convw W2
// | [13524,13528) sample1. All partitions independent.
#define PREP_CONVF   12500   // NFEAT*DIM/4/256
#define PREP_CONVW   512     // DIM*KTOT/256
#define PREP_BLOCKS  (PREP_CONVF + 2 * PREP_CONVW + 4)
__global__ __launch_bounds__(256) void prep_k(
    const float* __restrict__ feats, uint32_t* __restrict__ fb,
    const float* __restrict__ Wx1, const float* __restrict__ Wn1,
    unsigned short* __restrict__ Wt1,
    const float* __restrict__ Wx2, const float* __restrict__ Wn2,
    unsigned short* __restrict__ Wt2,
    const int* __restrict__ ids, const int* __restrict__ dix,
    const float* __restrict__ dval, int* __restrict__ idx1,
    float* __restrict__ w1, Perm25 pm) {
  int b = blockIdx.x, t = threadIdx.x;
  if (b < PREP_CONVF) {
    // feats fp32 -> packed bf16, 4 elem/thread
    int i = b * 256 + t;
    f32x4 v = *(const f32x4*)&feats[(size_t)i * 4];
    fb[(size_t)i * 2]     = f2bf(v.x) | ((uint32_t)f2bf(v.y) << 16);
    fb[(size_t)i * 2 + 1] = f2bf(v.z) | ((uint32_t)f2bf(v.w) << 16);
  } else if (b < PREP_CONVF + 2 * PREP_CONVW) {
    int wi = b - PREP_CONVF;
    const float* Wx = (wi < PREP_CONVW) ? Wx1 : Wx2;
    const float* Wn = (wi < PREP_CONVW) ? Wn1 : Wn2;
    unsigned short* Wt = (wi < PREP_CONVW) ? Wt1 : Wt2;
    int idx = (wi % PREP_CONVW) * 256 + t;
    int n = idx >> 9, k = idx & 511;
    float v = (k < DIM) ? Wx[(size_t)k * DIM + n] : Wn[(size_t)(k - DIM) * DIM + n];
    Wt[(size_t)n * KTOT + k] = f2bf(v);
  } else {
    // sample1: layer-0 neighbor sampling for the 1024 batch nodes
    int i = (b - PREP_CONVF - 2 * PREP_CONVW) * 256 + t;
    if (i >= BATCH) return;
    int nid = ids[i];
    const float* vr = dval + (size_t)nid * NNEIB;
    const int* ir = dix + (size_t)nid * NNEIB;
    float v[S1];
    float s = 0.f;
    for (int j = 0; j < S1; j++) { v[j] = vr[pm.p[j]]; s += v[j]; }
    float inv = 1.f / (s + 1e-10f);
    for (int j = 0; j < S1; j++) {
      w1[i * S1 + j] = v[j] * inv;
      idx1[i * S1 + j] = ir[pm.p[j]];
    }
  }
}

// stage1 (with inline layer-1 sampling): M1[r] = wmean of bf16 neighbor rows.
// Wave-per-row, 4 rows/block. Rows < BATCH use idx1/w1 (25 neib); rows >=
// BATCH sample 10 neib from dix/dval on the fly (shfl-sum normalizer keeps
// the same sequential fp32 add order as the old sample2 kernel).
__global__ __launch_bounds__(256) void stage1_k(
    const uint2* __restrict__ fb, const int* __restrict__ idx1,
    const float* __restrict__ w1, const int* __restrict__ dix,
    const float* __restrict__ dval, Perm10 pm2, uint2* __restrict__ M1) {
  int wave = threadIdx.x >> 6, lane = threadIdx.x & 63;
  int r = blockIdx.x * 4 + wave;
  int s, nbl = 0;
  float wl = 0.f;
  if (r < BATCH) {
    s = S1;
    if (lane < S1) { nbl = idx1[r * S1 + lane]; wl = w1[r * S1 + lane]; }
  } else {
    s = S2;
    int nx = idx1[r - BATCH];
    float vj = 0.f;
    if (lane < S2) {
      int c = pm2.p[lane];
      nbl = dix[(size_t)nx * NNEIB + c];
      vj = dval[(size_t)nx * NNEIB + c];
    }
    float tot = 0.f;
    for (int j = 0; j < S2; j++) tot += __shfl(vj, j);
    wl = vj / (tot + 1e-10f);
  }
  float a0 = 0.f, a1 = 0.f, a2 = 0.f, a3 = 0.f;
  for (int j = 0; j < s; j++) {
    int nid = __shfl(nbl, j);
    float wj = __shfl(wl, j);
    uint2 u = fb[(size_t)nid * 64 + lane];
    a0 += wj * bfbits2f(u.x & 0xffffu);
    a1 += wj * bfbits2f(u.x >> 16);
    a2 += wj * bfbits2f(u.y & 0xffffu);
    a3 += wj * bfbits2f(u.y >> 16);
  }
  uint2 o;
  o.x = f2bf(a0) | ((uint32_t)f2bf(a1) << 16);
  o.y = f2bf(a2) | ((uint32_t)f2bf(a3) << 16);
  M1[(size_t)r * 64 + lane] = o;
}

// stage2: M2[i] = wmean over H rows 1024+i*25+j with w1. Wave-per-row.
__global__ __launch_bounds__(256) void stage2_k(
    const uint2* __restrict__ Hb, const float* __restrict__ w1,
    uint2* __restrict__ M2) {
  int wave = threadIdx.x >> 6, lane = threadIdx.x & 63;
  int i = blockIdx.x * 4 + wave;
  float wl = (lane < S1) ? w1[(size_t)i * S1 + lane] : 0.f;
  const uint2* hb = Hb + (size_t)(BATCH + i * S1) * 64 + lane;
  float a0 = 0.f, a1 = 0.f, a2 = 0.f, a3 = 0.f;
  for (int j = 0; j < S1; j++) {
    float wj = __shfl(wl, j);
    uint2 u = hb[(size_t)j * 64];
    a0 += wj * bfbits2f(u.x & 0xffffu);
    a1 += wj * bfbits2f(u.x >> 16);
    a2 += wj * bfbits2f(u.y & 0xffffu);
    a3 += wj * bfbits2f(u.y >> 16);
  }
  uint2 o;
  o.x = f2bf(a0) | ((uint32_t)f2bf(a1) << 16);
  o.y = f2bf(a2) | ((uint32_t)f2bf(a3) << 16);
  M2[(size_t)i * 64 + lane] = o;
}

// bf16 MFMA GEMM with virtual A = [X | M]:
//   X[r][k]  = Xsrc[xrow(r)][k]   (k < 256), xrow via ids/idx1 (or identity)
//   M[r][k'] = Mh[r][k'-256]
// Out[M x 256] = relu(A @ Wt^T + bx + bn). 4 waves, 2x2 wave grid,
// 16x16x32 MFMA; fragment layouts HW-verified (m89/m91).
#define BK 32
#define LPAD 40   // LDS row stride (bf16): 80 B -> 2-way bank aliasing (free)
template <int TBM, int TBN, bool OUT_BF16>
__global__ __launch_bounds__(256) void gemm_k(
    const unsigned short* __restrict__ Xsrc, const int* __restrict__ ids,
    const int* __restrict__ idx1, const unsigned short* __restrict__ Mh,
    const unsigned short* __restrict__ Wt, const float* __restrict__ bx,
    const float* __restrict__ bn, void* __restrict__ OutP) {
  constexpr int MI = TBM / 32;
  constexpr int NJ = TBN / 32;
  __shared__ __align__(16) unsigned short As[TBM][LPAD];
  __shared__ __align__(16) unsigned short Bs[TBN][LPAD];
  int t = threadIdx.x;
  int wave = t >> 6, lane = t & 63, quad = lane >> 4, l16 = lane & 15;
  int wm = (wave >> 1) * (TBM / 2);
  int wn = (wave & 1) * (TBN / 2);
  int row0 = blockIdx.x * TBM, col0 = blockIdx.y * TBN;

  f32x4 acc[MI][NJ];
#pragma unroll
  for (int i = 0; i < MI; i++)
#pragma unroll
    for (int j = 0; j < NJ; j++) acc[i][j] = (f32x4){0.f, 0.f, 0.f, 0.f};

  int lr = t >> 2;
  int lq = (t & 3) * 8;
  int xrow[TBM / 64];
#pragma unroll
  for (int p = 0; p < TBM / 64; p++) {
    int gr = row0 + p * 64 + lr;
    xrow[p] = ids ? ((gr < BATCH) ? ids[gr] : idx1[gr - BATCH]) : gr;
  }

  for (int k0 = 0; k0 < KTOT; k0 += BK) {
#pragma unroll
    for (int p = 0; p < TBM / 64; p++) {
      const unsigned short* src =
          (k0 < DIM) ? (Xsrc + (size_t)xrow[p] * DIM + k0 + lq)
                     : (Mh + (size_t)(row0 + p * 64 + lr) * DIM + (k0 - DIM) + lq);
      *(f32x4*)&As[p * 64 + lr][lq] = *(const f32x4*)src;
    }
#pragma unroll
    for (int p = 0; p < TBN / 64; p++)
      *(f32x4*)&Bs[p * 64 + lr][lq] =
          *(const f32x4*)&Wt[(size_t)(col0 + p * 64 + lr) * KTOT + k0 + lq];
    __syncthreads();

    short8 af[MI], bfr[NJ];
#pragma unroll
    for (int i = 0; i < MI; i++)
      af[i] = *(const short8*)&As[wm + i * 16 + l16][quad * 8];
#pragma unroll
    for (int j = 0; j < NJ; j++)
      bfr[j] = *(const short8*)&Bs[wn + j * 16 + l16][quad * 8];
#pragma unroll
    for (int i = 0; i < MI; i++)
#pragma unroll
      for (int j = 0; j < NJ; j++)
        acc[i][j] = __builtin_amdgcn_mfma_f32_16x16x32_bf16(af[i], bfr[j], acc[i][j], 0, 0, 0);
    __syncthreads();
  }

  // Epilogue: bias + relu. D layout: col = l16, row = quad*4 + reg.
  float bias[NJ];
#pragma unroll
  for (int j = 0; j < NJ; j++) {
    int c = col0 + wn + j * 16 + l16;
    bias[j] = bx[c] + bn[c];
  }
#pragma unroll
  for (int i = 0; i < MI; i++) {
#pragma unroll
    for (int j = 0; j < NJ; j++) {
      int c = col0 + wn + j * 16 + l16;
#pragma unroll
      for (int reg = 0; reg < 4; reg++) {
        int r = row0 + wm + i * 16 + quad * 4 + reg;
        float v = fmaxf(acc[i][j][reg] + bias[j], 0.f);
        if (OUT_BF16)
          ((unsigned short*)OutP)[(size_t)r * DIM + c] = f2bf(v);
        else
          ((float*)OutP)[(size_t)r * DIM + c] = v;
      }
    }
  }
}

// ================================ launcher ===================================
static inline size_t align256(size_t x) { return (x + 255) & ~(size_t)255; }

extern "C" void kernel_launch(void* const* d_in, const int* in_sizes, int n_in,
                              void* d_out, int out_size, void* d_ws, size_t ws_size,
                              hipStream_t stream) {
  const int*   ids  = (const int*)d_in[0];
  const int*   dix  = (const int*)d_in[1];
  const float* dval = (const float*)d_in[2];
  const float* feats= (const float*)d_in[3];
  const float* Wx1  = (const float*)d_in[4];
  const float* bx1  = (const float*)d_in[5];
  const float* Wn1  = (const float*)d_in[6];
  const float* bn1  = (const float*)d_in[7];
  const float* Wx2  = (const float*)d_in[8];
  const float* bx2  = (const float*)d_in[9];
  const float* Wn2  = (const float*)d_in[10];
  const float* bn2  = (const float*)d_in[11];
  float* out = (float*)d_out;

  Perm25 p25;
  Perm10 p10;
  compute_perm(0u, S1, p25.p);
  compute_perm(1u, S2, p10.p);

  // Workspace carve-up (~54 MB).
  char* w = (char*)d_ws;
  int*            idx1 = (int*)w;            w += align256(sizeof(int) * L2ROWS);
  float*          w1   = (float*)w;          w += align256(sizeof(float) * L2ROWS);
  uint32_t*       fb   = (uint32_t*)w;       w += align256(2 * (size_t)NFEAT * DIM);
  unsigned short* M1   = (unsigned short*)w; w += align256(2 * (size_t)MROWS * DIM);
  unsigned short* Hb   = (unsigned short*)w; w += align256(2 * (size_t)MROWS * DIM);
  unsigned short* M2   = (unsigned short*)w; w += align256(2 * (size_t)BATCH * DIM);
  unsigned short* Wt1  = (unsigned short*)w; w += align256(2 * (size_t)DIM * KTOT);
  unsigned short* Wt2  = (unsigned short*)w; w += align256(2 * (size_t)DIM * KTOT);

  prep_k<<<PREP_BLOCKS, 256, 0, stream>>>(feats, fb, Wx1, Wn1, Wt1, Wx2, Wn2, Wt2,
                                          ids, dix, dval, idx1, w1, p25);
  stage1_k<<<MROWS / 4, 256, 0, stream>>>((const uint2*)fb, idx1, w1, dix, dval, p10,
                                          (uint2*)M1);
  gemm_k<128, 128, true><<<dim3(MROWS / 128, DIM / 128), 256, 0, stream>>>(
      (const unsigned short*)fb, ids, idx1, M1, Wt1, bx1, bn1, Hb);
  stage2_k<<<BATCH / 4, 256, 0, stream>>>((const uint2*)Hb, w1, (uint2*)M2);
  gemm_k<64, 64, false><<<dim3(BATCH / 64, DIM / 64), 256, 0, stream>>>(
      Hb, nullptr, nullptr, M2, Wt2, bx2, bn2, out);
}